// Round 1
// baseline (809.830 us; speedup 1.0000x reference)
//
#include <hip/hip_runtime.h>
#include <hip/hip_bf16.h>
#include <cstdio>
#include <cstdint>

#define T_TOK   8192
#define H_DIM   1024
#define I_DIM   2048
#define E_NUM   8
#define BM      128
#define BN      128
#define BK      32
#define LDK     40            // BK + 8 bf16 pad -> 80B row stride (16B aligned, 2-way banks)
#define PADMAX  17408         // T*K + E*BM
#define MAX_TILES 136         // T*K/BM + E

#define OUT_FRAC  8388608
#define OUT_AVG   8388616
#define OUT_LOG   8388624
#define OUT_PROB  8454160

typedef short short8v __attribute__((ext_vector_type(8)));
typedef float f32x4   __attribute__((ext_vector_type(4)));

__device__ __forceinline__ uint32_t f2bf(float f){
  union { float f; uint32_t u; } v; v.f = f;
  return (v.u + 0x7FFFu + ((v.u >> 16) & 1u)) >> 16;   // RNE
}
__device__ __forceinline__ uint32_t pack2(float a, float b){
  return f2bf(a) | (f2bf(b) << 16);
}

// ---------------- hidden fp32 -> bf16 ----------------
__global__ __launch_bounds__(256) void convert_kernel(const float* __restrict__ x,
                                                      ushort* __restrict__ xb){
  size_t i = ((size_t)blockIdx.x * 256 + threadIdx.x) * 8;
  float4 f0 = *(const float4*)(x + i);
  float4 f1 = *(const float4*)(x + i + 4);
  uint4 o;
  o.x = pack2(f0.x, f0.y); o.y = pack2(f0.z, f0.w);
  o.z = pack2(f1.x, f1.y); o.w = pack2(f1.z, f1.w);
  *(uint4*)(xb + i) = o;
}

// ---------------- router: logits/softmax/top2 ----------------
__global__ __launch_bounds__(256) void router_kernel(const float* __restrict__ x,
    const float* __restrict__ rw, float* __restrict__ out,
    int* __restrict__ counts, int* __restrict__ pe, float* __restrict__ pw){
  __shared__ float s_rw[E_NUM * H_DIM];
  __shared__ float s_avg[E_NUM];
  const int tid = threadIdx.x;
  for (int i = tid; i < E_NUM*H_DIM/4; i += 256)
    ((float4*)s_rw)[i] = ((const float4*)rw)[i];
  if (tid < E_NUM) s_avg[tid] = 0.f;
  __syncthreads();
  const int lane = tid & 63;
  const int t = blockIdx.x * 4 + (tid >> 6);
  float acc[E_NUM];
  #pragma unroll
  for (int e=0;e<E_NUM;e++) acc[e] = 0.f;
  const float* xr = x + (size_t)t * H_DIM;
  for (int c=0;c<H_DIM/64;c++){
    float xv = xr[c*64 + lane];
    #pragma unroll
    for (int e=0;e<E_NUM;e++) acc[e] += xv * s_rw[e*H_DIM + c*64 + lane];
  }
  #pragma unroll
  for (int e=0;e<E_NUM;e++){
    #pragma unroll
    for (int off=32; off; off>>=1) acc[e] += __shfl_xor(acc[e], off);
  }
  if (lane == 0){
    float m = acc[0];
    #pragma unroll
    for (int e=1;e<E_NUM;e++) m = fmaxf(m, acc[e]);
    float p[E_NUM]; float s = 0.f;
    #pragma unroll
    for (int e=0;e<E_NUM;e++){ p[e] = __expf(acc[e]-m); s += p[e]; }
    float inv = 1.f/s;
    #pragma unroll
    for (int e=0;e<E_NUM;e++) p[e] *= inv;
    float* lg = out + OUT_LOG  + (size_t)t*E_NUM;
    float* pr = out + OUT_PROB + (size_t)t*E_NUM;
    #pragma unroll
    for (int e=0;e<E_NUM;e++){ lg[e] = acc[e]; pr[e] = p[e]; }
    #pragma unroll
    for (int e=0;e<E_NUM;e++) atomicAdd(&s_avg[e], p[e]);
    int e1 = 0; float p1 = p[0];
    #pragma unroll
    for (int e=1;e<E_NUM;e++) if (p[e] > p1){ p1 = p[e]; e1 = e; }
    int e2 = -1; float p2 = -1.f;
    #pragma unroll
    for (int e=0;e<E_NUM;e++) if (e != e1 && p[e] > p2){ p2 = p[e]; e2 = e; }
    float rs = 1.f/(p1+p2);
    pe[2*t]   = e1; pw[2*t]   = p1*rs;
    pe[2*t+1] = e2; pw[2*t+1] = p2*rs;
    atomicAdd(&counts[e1], 1);
    atomicAdd(&counts[e2], 1);
  }
  __syncthreads();
  if (tid < E_NUM) atomicAdd(out + OUT_AVG + tid, s_avg[tid]);
}

// ---------------- offsets + tile table + zero-fill pads ----------------
__global__ void offsets_kernel(const int* __restrict__ counts, int* __restrict__ pad_off,
                               int* __restrict__ tile_e, int* __restrict__ tile_r,
                               int* __restrict__ hdr, int* __restrict__ s_tok,
                               float* __restrict__ s_wt){
  if (threadIdx.x == 0){
    int base = 0, tt = 0;
    for (int e=0;e<E_NUM;e++){
      pad_off[e] = base;
      int nt = (counts[e] + BM - 1) / BM;
      for (int i=0;i<nt;i++){ tile_e[tt] = e; tile_r[tt] = base + i*BM; tt++; }
      base += nt * BM;
    }
    hdr[0] = tt; hdr[1] = base;
  }
  for (int i = threadIdx.x; i < PADMAX; i += blockDim.x){
    s_tok[i] = 0; s_wt[i] = 0.f;
  }
}

// ---------------- scatter pairs into expert-sorted order ----------------
__global__ __launch_bounds__(256) void scatter_kernel(const int* __restrict__ pe,
    const float* __restrict__ pw, const int* __restrict__ pad_off,
    int* __restrict__ cursors, int* __restrict__ s_tok, float* __restrict__ s_wt){
  int t = blockIdx.x * 256 + threadIdx.x;
  #pragma unroll
  for (int k=0;k<2;k++){
    int e = pe[2*t + k];
    int pos = atomicAdd(&cursors[e], 1);
    int idx = pad_off[e] + pos;
    s_tok[idx] = t;
    s_wt[idx]  = pw[2*t + k];
  }
}

// ---------------- gate+up GEMM + SwiGLU -> h1 (bf16) ----------------
__global__ __launch_bounds__(256) void gateup_kernel(
    const ushort* __restrict__ xb, const float* __restrict__ gw,
    const float* __restrict__ uw, const int* __restrict__ s_tok,
    const int* __restrict__ tile_e, const int* __restrict__ tile_r,
    const int* __restrict__ hdr, ushort* __restrict__ h1)
{
  const int tile = blockIdx.y;
  if (tile >= hdr[0]) return;
  __shared__ short sA[2][BM*LDK];
  __shared__ short sG[2][BN*LDK];
  __shared__ short sU[2][BN*LDK];
  const int e = tile_e[tile];
  const int row0 = tile_r[tile];
  const int n0 = blockIdx.x * BN;
  const int tid = threadIdx.x;

  const int r0 = tid >> 2, c0 = (tid & 3) * 8;   // slot rows r0 / r0+64
  const uint4*  asrc0 = (const uint4*)(xb + (size_t)s_tok[row0 + r0]      * H_DIM) + (c0 >> 3);
  const uint4*  asrc1 = (const uint4*)(xb + (size_t)s_tok[row0 + r0 + 64] * H_DIM) + (c0 >> 3);
  const float4* gsrc0 = (const float4*)(gw + (size_t)e*I_DIM*H_DIM + (size_t)(n0 + r0)      * H_DIM) + (c0 >> 2);
  const float4* gsrc1 = (const float4*)(gw + (size_t)e*I_DIM*H_DIM + (size_t)(n0 + r0 + 64) * H_DIM) + (c0 >> 2);
  const float4* usrc0 = (const float4*)(uw + (size_t)e*I_DIM*H_DIM + (size_t)(n0 + r0)      * H_DIM) + (c0 >> 2);
  const float4* usrc1 = (const float4*)(uw + (size_t)e*I_DIM*H_DIM + (size_t)(n0 + r0 + 64) * H_DIM) + (c0 >> 2);
  const int off0 = r0*LDK + c0, off1 = (r0+64)*LDK + c0;

  const int lane = tid & 63, wid = tid >> 6;
  const int wm = (wid >> 1) * 64, wn = (wid & 1) * 64;
  const int lr = lane & 15, ko = (lane >> 4) * 8;

  f32x4 accG[4][4] = {};
  f32x4 accU[4][4] = {};
  uint4 ra0, ra1; float4 rb0, rb1, rb2, rb3, rb4, rb5, rb6, rb7;

  // prologue: stage kt=0 into buf 0
  ra0 = asrc0[0]; ra1 = asrc1[0];
  rb0 = gsrc0[0]; rb1 = gsrc0[1]; rb2 = gsrc1[0]; rb3 = gsrc1[1];
  rb4 = usrc0[0]; rb5 = usrc0[1]; rb6 = usrc1[0]; rb7 = usrc1[1];
  *(uint4*)&sA[0][off0] = ra0;
  *(uint4*)&sA[0][off1] = ra1;
  *(uint4*)&sG[0][off0] = make_uint4(pack2(rb0.x,rb0.y),pack2(rb0.z,rb0.w),pack2(rb1.x,rb1.y),pack2(rb1.z,rb1.w));
  *(uint4*)&sG[0][off1] = make_uint4(pack2(rb2.x,rb2.y),pack2(rb2.z,rb2.w),pack2(rb3.x,rb3.y),pack2(rb3.z,rb3.w));
  *(uint4*)&sU[0][off0] = make_uint4(pack2(rb4.x,rb4.y),pack2(rb4.z,rb4.w),pack2(rb5.x,rb5.y),pack2(rb5.z,rb5.w));
  *(uint4*)&sU[0][off1] = make_uint4(pack2(rb6.x,rb6.y),pack2(rb6.z,rb6.w),pack2(rb7.x,rb7.y),pack2(rb7.z,rb7.w));
  __syncthreads();

  const int NK = H_DIM / BK;  // 32
  for (int kt = 0; kt < NK; ++kt){
    const int buf = kt & 1;
    if (kt + 1 < NK){
      ra0 = asrc0[(kt+1)*4]; ra1 = asrc1[(kt+1)*4];
      rb0 = gsrc0[(kt+1)*8]; rb1 = gsrc0[(kt+1)*8+1];
      rb2 = gsrc1[(kt+1)*8]; rb3 = gsrc1[(kt+1)*8+1];
      rb4 = usrc0[(kt+1)*8]; rb5 = usrc0[(kt+1)*8+1];
      rb6 = usrc1[(kt+1)*8]; rb7 = usrc1[(kt+1)*8+1];
    }
    short8v a[4];
    #pragma unroll
    for (int mi=0;mi<4;mi++)
      a[mi] = *(const short8v*)&sA[buf][(wm + mi*16 + lr)*LDK + ko];
    #pragma unroll
    for (int ni=0;ni<4;ni++){
      short8v bg = *(const short8v*)&sG[buf][(wn + ni*16 + lr)*LDK + ko];
      short8v bu = *(const short8v*)&sU[buf][(wn + ni*16 + lr)*LDK + ko];
      #pragma unroll
      for (int mi=0;mi<4;mi++){
        accG[mi][ni] = __builtin_amdgcn_mfma_f32_16x16x32_bf16(a[mi], bg, accG[mi][ni], 0,0,0);
        accU[mi][ni] = __builtin_amdgcn_mfma_f32_16x16x32_bf16(a[mi], bu, accU[mi][ni], 0,0,0);
      }
    }
    if (kt + 1 < NK){
      const int nb = buf ^ 1;
      *(uint4*)&sA[nb][off0] = ra0;
      *(uint4*)&sA[nb][off1] = ra1;
      *(uint4*)&sG[nb][off0] = make_uint4(pack2(rb0.x,rb0.y),pack2(rb0.z,rb0.w),pack2(rb1.x,rb1.y),pack2(rb1.z,rb1.w));
      *(uint4*)&sG[nb][off1] = make_uint4(pack2(rb2.x,rb2.y),pack2(rb2.z,rb2.w),pack2(rb3.x,rb3.y),pack2(rb3.z,rb3.w));
      *(uint4*)&sU[nb][off0] = make_uint4(pack2(rb4.x,rb4.y),pack2(rb4.z,rb4.w),pack2(rb5.x,rb5.y),pack2(rb5.z,rb5.w));
      *(uint4*)&sU[nb][off1] = make_uint4(pack2(rb6.x,rb6.y),pack2(rb6.z,rb6.w),pack2(rb7.x,rb7.y),pack2(rb7.z,rb7.w));
    }
    __syncthreads();
  }

  // epilogue: h1 = silu(g) * u  (bf16)
  #pragma unroll
  for (int mi=0;mi<4;mi++){
    #pragma unroll
    for (int r=0;r<4;r++){
      const int row = row0 + wm + mi*16 + (lane>>4)*4 + r;
      ushort* hp = h1 + (size_t)row * I_DIM + n0 + wn + lr;
      #pragma unroll
      for (int ni=0;ni<4;ni++){
        float g = accG[mi][ni][r], u = accU[mi][ni][r];
        float sv = g / (1.f + __expf(-g));
        hp[ni*16] = (ushort)f2bf(sv * u);
      }
    }
  }
}

// ---------------- down GEMM -> weighted scatter-add into output ----------------
__global__ __launch_bounds__(256) void down_kernel(
    const ushort* __restrict__ h1, const float* __restrict__ dw,
    const int* __restrict__ s_tok, const float* __restrict__ s_wt,
    const int* __restrict__ tile_e, const int* __restrict__ tile_r,
    const int* __restrict__ hdr, float* __restrict__ out)
{
  const int tile = blockIdx.y;
  if (tile >= hdr[0]) return;
  __shared__ short sA[2][BM*LDK];
  __shared__ short sB[2][BN*LDK];
  const int e = tile_e[tile];
  const int row0 = tile_r[tile];
  const int n0 = blockIdx.x * BN;
  const int tid = threadIdx.x;

  const int r0 = tid >> 2, c0 = (tid & 3) * 8;
  const uint4*  asrc0 = (const uint4*)(h1 + (size_t)(row0 + r0)      * I_DIM) + (c0 >> 3);
  const uint4*  asrc1 = (const uint4*)(h1 + (size_t)(row0 + r0 + 64) * I_DIM) + (c0 >> 3);
  const float4* bsrc0 = (const float4*)(dw + (size_t)e*H_DIM*I_DIM + (size_t)(n0 + r0)      * I_DIM) + (c0 >> 2);
  const float4* bsrc1 = (const float4*)(dw + (size_t)e*H_DIM*I_DIM + (size_t)(n0 + r0 + 64) * I_DIM) + (c0 >> 2);
  const int off0 = r0*LDK + c0, off1 = (r0+64)*LDK + c0;

  const int lane = tid & 63, wid = tid >> 6;
  const int wm = (wid >> 1) * 64, wn = (wid & 1) * 64;
  const int lr = lane & 15, ko = (lane >> 4) * 8;

  f32x4 acc[4][4] = {};
  uint4 ra0, ra1; float4 rb0, rb1, rb2, rb3;

  ra0 = asrc0[0]; ra1 = asrc1[0];
  rb0 = bsrc0[0]; rb1 = bsrc0[1]; rb2 = bsrc1[0]; rb3 = bsrc1[1];
  *(uint4*)&sA[0][off0] = ra0;
  *(uint4*)&sA[0][off1] = ra1;
  *(uint4*)&sB[0][off0] = make_uint4(pack2(rb0.x,rb0.y),pack2(rb0.z,rb0.w),pack2(rb1.x,rb1.y),pack2(rb1.z,rb1.w));
  *(uint4*)&sB[0][off1] = make_uint4(pack2(rb2.x,rb2.y),pack2(rb2.z,rb2.w),pack2(rb3.x,rb3.y),pack2(rb3.z,rb3.w));
  __syncthreads();

  const int NK = I_DIM / BK;  // 64
  for (int kt = 0; kt < NK; ++kt){
    const int buf = kt & 1;
    if (kt + 1 < NK){
      ra0 = asrc0[(kt+1)*4]; ra1 = asrc1[(kt+1)*4];
      rb0 = bsrc0[(kt+1)*8]; rb1 = bsrc0[(kt+1)*8+1];
      rb2 = bsrc1[(kt+1)*8]; rb3 = bsrc1[(kt+1)*8+1];
    }
    short8v a[4];
    #pragma unroll
    for (int mi=0;mi<4;mi++)
      a[mi] = *(const short8v*)&sA[buf][(wm + mi*16 + lr)*LDK + ko];
    #pragma unroll
    for (int ni=0;ni<4;ni++){
      short8v b = *(const short8v*)&sB[buf][(wn + ni*16 + lr)*LDK + ko];
      #pragma unroll
      for (int mi=0;mi<4;mi++)
        acc[mi][ni] = __builtin_amdgcn_mfma_f32_16x16x32_bf16(a[mi], b, acc[mi][ni], 0,0,0);
    }
    if (kt + 1 < NK){
      const int nb = buf ^ 1;
      *(uint4*)&sA[nb][off0] = ra0;
      *(uint4*)&sA[nb][off1] = ra1;
      *(uint4*)&sB[nb][off0] = make_uint4(pack2(rb0.x,rb0.y),pack2(rb0.z,rb0.w),pack2(rb1.x,rb1.y),pack2(rb1.z,rb1.w));
      *(uint4*)&sB[nb][off1] = make_uint4(pack2(rb2.x,rb2.y),pack2(rb2.z,rb2.w),pack2(rb3.x,rb3.y),pack2(rb3.z,rb3.w));
    }
    __syncthreads();
  }

  #pragma unroll
  for (int mi=0;mi<4;mi++){
    #pragma unroll
    for (int r=0;r<4;r++){
      const int prow = row0 + wm + mi*16 + (lane>>4)*4 + r;
      const float wgt = s_wt[prow];
      if (wgt != 0.f){
        const int tok = s_tok[prow];
        float* op = out + (size_t)tok * H_DIM + n0 + wn + lr;
        #pragma unroll
        for (int ni=0;ni<4;ni++)
          atomicAdd(op + ni*16, acc[mi][ni][r] * wgt);
      }
    }
  }
}

// ---------------- finalize expert_frac / avg_prob ----------------
__global__ void finalize_kernel(const int* __restrict__ counts, float* __restrict__ out){
  int t = threadIdx.x;
  if (t < E_NUM){
    out[OUT_FRAC + t] = (float)counts[t] * (1.f/16384.f);
    out[OUT_AVG  + t] *= (1.f/8192.f);
  }
}

extern "C" void kernel_launch(void* const* d_in, const int* in_sizes, int n_in,
                              void* d_out, int out_size, void* d_ws, size_t ws_size,
                              hipStream_t stream){
  const float* x   = (const float*)d_in[0];
  const float* rw  = (const float*)d_in[1];
  const float* gw  = (const float*)d_in[2];
  const float* uw  = (const float*)d_in[3];
  const float* dwn = (const float*)d_in[4];
  float* out = (float*)d_out;

  char* w = (char*)d_ws;
  int*   counts  = (int*)(w + 0);
  int*   cursors = (int*)(w + 32);
  int*   hdr     = (int*)(w + 64);
  int*   pad_off = (int*)(w + 96);
  int*   tile_e  = (int*)(w + 256);
  int*   tile_r  = (int*)(w + 1024);
  int*   s_tok   = (int*)(w + 4096);
  float* s_wt    = (float*)(w + 4096 + PADMAX*4);
  int*   pe      = (int*)(w + 4096 + PADMAX*8);
  float* pw      = (float*)(w + 4096 + PADMAX*8 + T_TOK*2*4);
  ushort* xb     = (ushort*)(w + 274432);
  ushort* h1     = (ushort*)(w + 274432 + (size_t)T_TOK*H_DIM*2);

  size_t need = 274432 + (size_t)T_TOK*H_DIM*2 + (size_t)PADMAX*I_DIM*2;
  if (ws_size < need){
    fprintf(stderr, "kernel_launch: ws too small (%zu < %zu)\n", ws_size, need);
    return;
  }

  hipMemsetAsync(out, 0, (size_t)(OUT_AVG + E_NUM) * 4, stream);
  hipMemsetAsync(d_ws, 0, 4096, stream);
  convert_kernel<<<T_TOK*H_DIM/(256*8), 256, 0, stream>>>(x, xb);
  router_kernel<<<T_TOK/4, 256, 0, stream>>>(x, rw, out, counts, pe, pw);
  offsets_kernel<<<1, 256, 0, stream>>>(counts, pad_off, tile_e, tile_r, hdr, s_tok, s_wt);
  scatter_kernel<<<T_TOK/256, 256, 0, stream>>>(pe, pw, pad_off, cursors, s_tok, s_wt);
  gateup_kernel<<<dim3(I_DIM/BN, MAX_TILES), 256, 0, stream>>>(xb, gw, uw, s_tok, tile_e, tile_r, hdr, h1);
  down_kernel<<<dim3(H_DIM/BN, MAX_TILES), 256, 0, stream>>>(h1, dwn, s_tok, s_wt, tile_e, tile_r, hdr, out);
  finalize_kernel<<<1, 64, 0, stream>>>(counts, out);
}